// Round 6
// baseline (353.542 us; speedup 1.0000x reference)
//
#include <hip/hip_runtime.h>
#include <hip/hip_fp16.h>
#include <math.h>

#define C_S 256
#define NUM_HEADS 8
#define HEAD_DIM 32
#define TOTAL 256
#define S_DIM 256
#define I_DIM 256
#define NROWS (S_DIM * I_DIM)   // 65536
#define LN_EPS 1e-5f
#define QSCALE 0.25503534f      // log2(e)/sqrt(32)

typedef _Float16 f16x8 __attribute__((ext_vector_type(8)));   // 8 fp16 = 4 VGPR
typedef __attribute__((ext_vector_type(4))) float f32x4;

__device__ __forceinline__ ushort f2h(float x) {
  return __half_as_ushort(__float2half(x));      // RNE
}
__device__ __forceinline__ float h2f(ushort u) {
  return __half2float(__ushort_as_half(u));
}
// pack two f32 -> fp16x2 dword, RNE (cold paths)
__device__ __forceinline__ uint pk2(float a, float b) {
  return (uint)f2h(a) | ((uint)f2h(b) << 16);
}
// pack two f32 -> two fp16 (RTZ) in one VALU op; returns the 32-bit word
__device__ __forceinline__ uint pkrtz(float a, float b) {
  return __builtin_bit_cast(uint, __builtin_amdgcn_cvt_pkrtz(a, b));
}
// async global->LDS, 16B per lane; lds base must be wave-uniform.
__device__ __forceinline__ void gl16(const void* g, void* l) {
  __builtin_amdgcn_global_load_lds(
      (const __attribute__((address_space(1))) unsigned*)g,
      (__attribute__((address_space(3))) unsigned*)l, 16, 0, 0);
}
// quad all-to-all within same lr: inputs (x0 = block0 dword, x1 = block1 dword)
// outputs: o0 = dword for src-quads {2(q&1)}, o1 = for {2(q&1)+1}, block q>>1.
__device__ __forceinline__ void quadx(uint x0, uint x1, uint& o0, uint& o1) {
  auto a = __builtin_amdgcn_permlane32_swap(x0, x1, false, false);
  auto b = __builtin_amdgcn_permlane16_swap(a[0], a[1], false, false);
  o0 = b[0]; o1 = b[1];
}

// ---------------------------------------------------------------------------
// prep_w: transpose + fp16-convert weights once.
// QKVG -> combined [1024][256] fp16 (row = mat*256+n, k contiguous);
// Wo -> [256][256] fp16.
// ---------------------------------------------------------------------------
__global__ __launch_bounds__(256) void prep_w_kernel(
    const float* __restrict__ Wq, const float* __restrict__ Wk,
    const float* __restrict__ Wv, const float* __restrict__ Wg,
    const float* __restrict__ Wo,
    ushort* __restrict__ Wch, ushort* __restrict__ Woh) {
  const int b = blockIdx.x;            // 0..1279
  const int mat = b >> 8, n = b & 255;
  const int k = threadIdx.x;
  const float* W = (mat == 0) ? Wq : (mat == 1) ? Wk
                  : (mat == 2) ? Wv : (mat == 3) ? Wg : Wo;
  ushort h = f2h(W[(size_t)k * 256 + n]);
  if (mat < 4) Wch[((size_t)(mat * 256 + n)) * 256 + k] = h;
  else         Woh[(size_t)n * 256 + k] = h;
}

// ---------------------------------------------------------------------------
// prep_x: LN stats + apply + fp16-convert, once. One wave per row.
// X fp16 lives in d_out (dead until out_kernel overwrites it).
// ---------------------------------------------------------------------------
__global__ __launch_bounds__(256) void prep_x_kernel(
    const float* __restrict__ msa, const float* __restrict__ gamma,
    const float* __restrict__ beta, ushort* __restrict__ Xh) {
  const int row  = blockIdx.x * 4 + (threadIdx.x >> 6);
  const int lane = threadIdx.x & 63;
  float4 v = ((const float4*)(msa + (size_t)row * C_S))[lane];
  float sum = v.x + v.y + v.z + v.w;
  float sq  = v.x*v.x + v.y*v.y + v.z*v.z + v.w*v.w;
  #pragma unroll
  for (int off = 1; off < 64; off <<= 1) {
    sum += __shfl_xor(sum, off);
    sq  += __shfl_xor(sq, off);
  }
  float mu = sum * (1.0f / 256.0f);
  float rs = rsqrtf(sq * (1.0f / 256.0f) - mu * mu + LN_EPS);
  float4 gv = ((const float4*)gamma)[lane];
  float4 bv = ((const float4*)beta)[lane];
  ushort4 hh;
  hh.x = f2h((v.x - mu) * rs * gv.x + bv.x);
  hh.y = f2h((v.y - mu) * rs * gv.y + bv.y);
  hh.z = f2h((v.z - mu) * rs * gv.z + bv.z);
  hh.w = f2h((v.w - mu) * rs * gv.w + bv.w);
  *(ushort4*)(Xh + (size_t)row * 256 + lane * 4) = hh;
}

// ---------------------------------------------------------------------------
// fused_attn: one block per (i,h). 256 threads / 4 waves; wave owns 64 rows.
//  LDS 36.5 KB (fits 4 blocks/CU):
//   Kls[256][40]  K[t][d]                                       20.0 KB
//   Vth[32][264]  V^T[d][t]  (filled by swapped-operand MFMA)   16.5 KB
//  REGISTER BUDGET is the occupancy limiter (gfx950 unified VGPR+AGPR).
//  (256,4) = 128-reg budget. To fit without spill (R4 lesson):
//   - the 4 projection GEMMs run as 4 SEQUENTIAL passes (K,V,Q,G), so only
//     ONE 32-reg accumulator is live at a time (X re-read 4x; X is
//     L3-resident, read BW was 130 GB/s -> free).
//   - gate is sigmoid'ed + fp16-packed right after the G pass (16 dwords
//     loop-carried instead of 32 f32).
//  P never touches LDS: QK-D -> PV-B shuffle is a quad exchange within
//  {lr, lr+16, lr+32, lr+48} via permlane32_swap + permlane16_swap.
//  Falsifier: if WRITE_SIZE >> 33 MB, spill returned -> revert to (256,3).
// ---------------------------------------------------------------------------
__global__ __launch_bounds__(256, 4) void fused_attn_kernel(
    const ushort* __restrict__ Xh,    // [65536][256], row = s*256+i
    const ushort* __restrict__ Wch,   // [1024][256], row = mat*256+n
    const float* __restrict__ bg,
    ushort* __restrict__ Oh) {        // (i,h,s,d) fp16
  __shared__ __align__(16) ushort Kls[256][40];   // 20.0 KB  K[t][d]
  __shared__ __align__(16) ushort Vth[32][264];   // 16.5 KB  V^T[d][t]

  const int bid = blockIdx.x;
  const int xcd = bid & 7, j = bid >> 3;
  const int h = j & 7;
  const int i = (xcd << 5) + (j >> 3);            // 32 consecutive i per XCD
  const int ih = i * NUM_HEADS + h;
  const int tid = threadIdx.x;
  const int wave = tid >> 6, lane = tid & 63;
  const int lr = lane & 15, quad = lane >> 4;
  const int s_base = wave * 64;
  const size_t hbase = (size_t)ih * (S_DIM * HEAD_DIM);

  // X B-frag base: row (s,i) = (s*256+i), element quad*8 within k-chunk
  const ushort* xr0 = Xh + ((size_t)(s_base + lr) * 256 + i) * 256 + quad * 8;
  // W^T A-frag base: row = mat*256 + h*32 + (mt*16+lr)
  const ushort* wr0 = Wch + ((size_t)(h * 32 + lr)) * 256 + quad * 8;

  // ---- Pass K (mat 1): normal operands, store K[t][d] ----
  {
    f32x4 kacc[2][4] = {};
    #pragma unroll
    for (int kb = 0; kb < 8; ++kb) {
      f16x8 xb[4];
      #pragma unroll
      for (int nt = 0; nt < 4; ++nt)
        xb[nt] = *(const f16x8*)(xr0 + (size_t)nt * 16 * 65536 + kb * 32);
      f16x8 wk[2];
      #pragma unroll
      for (int mt = 0; mt < 2; ++mt)
        wk[mt] = *(const f16x8*)(wr0 + (size_t)1 * 65536 + mt * 4096 + kb * 32);
      #pragma unroll
      for (int mt = 0; mt < 2; ++mt)
        #pragma unroll
        for (int nt = 0; nt < 4; ++nt)
          kacc[mt][nt] = __builtin_amdgcn_mfma_f32_16x16x32_f16(wk[mt], xb[nt], kacc[mt][nt], 0, 0, 0);
    }
    #pragma unroll
    for (int mt = 0; mt < 2; ++mt)
      #pragma unroll
      for (int nt = 0; nt < 4; ++nt) {
        // K: D col = t (nt*16+lr), row = d (mt*16+quad*4+reg)
        const int t = s_base + nt * 16 + lr;
        ushort4 kp;
        kp.x = f2h(kacc[mt][nt][0]); kp.y = f2h(kacc[mt][nt][1]);
        kp.z = f2h(kacc[mt][nt][2]); kp.w = f2h(kacc[mt][nt][3]);
        *(ushort4*)&Kls[t][mt * 16 + quad * 4] = kp;
      }
  }

  // ---- Pass V (mat 2): swapped operands -> packed V^T store ----
  {
    f32x4 vacc[2][4] = {};
    #pragma unroll
    for (int kb = 0; kb < 8; ++kb) {
      f16x8 xb[4];
      #pragma unroll
      for (int nt = 0; nt < 4; ++nt)
        xb[nt] = *(const f16x8*)(xr0 + (size_t)nt * 16 * 65536 + kb * 32);
      f16x8 wv[2];
      #pragma unroll
      for (int mt = 0; mt < 2; ++mt)
        wv[mt] = *(const f16x8*)(wr0 + (size_t)2 * 65536 + mt * 4096 + kb * 32);
      #pragma unroll
      for (int mt = 0; mt < 2; ++mt)
        #pragma unroll
        for (int nt = 0; nt < 4; ++nt)
          vacc[mt][nt] = __builtin_amdgcn_mfma_f32_16x16x32_f16(xb[nt], wv[mt], vacc[mt][nt], 0, 0, 0);
    }
    #pragma unroll
    for (int mt = 0; mt < 2; ++mt)
      #pragma unroll
      for (int nt = 0; nt < 4; ++nt) {
        // lane holds V^T[d = mt*16+lr][t = s_base+nt*16+quad*4+reg]
        ushort4 vp;
        vp.x = f2h(vacc[mt][nt][0]); vp.y = f2h(vacc[mt][nt][1]);
        vp.z = f2h(vacc[mt][nt][2]); vp.w = f2h(vacc[mt][nt][3]);
        *(ushort4*)&Vth[mt * 16 + lr][s_base + nt * 16 + quad * 4] = vp;
      }
  }

  // ---- Pass Q (mat 0): accumulate, then build B-operand frags in regs ----
  f16x8 qf[4];
  {
    f32x4 qacc[2][4] = {};
    #pragma unroll
    for (int kb = 0; kb < 8; ++kb) {
      f16x8 xb[4];
      #pragma unroll
      for (int nt = 0; nt < 4; ++nt)
        xb[nt] = *(const f16x8*)(xr0 + (size_t)nt * 16 * 65536 + kb * 32);
      f16x8 wq[2];
      #pragma unroll
      for (int mt = 0; mt < 2; ++mt)
        wq[mt] = *(const f16x8*)(wr0 + (size_t)0 * 65536 + mt * 4096 + kb * 32);
      #pragma unroll
      for (int mt = 0; mt < 2; ++mt)
        #pragma unroll
        for (int nt = 0; nt < 4; ++nt)
          qacc[mt][nt] = __builtin_amdgcn_mfma_f32_16x16x32_f16(wq[mt], xb[nt], qacc[mt][nt], 0, 0, 0);
    }
    // Source: lane holds Q[d = mt*16+quad*4+reg][s = ns*16+lr].
    // Dest: qf[ns] lane needs k=d = quad*8+j  -> quadx recipe (RNE pack).
    #pragma unroll
    for (int ns = 0; ns < 4; ++ns) {
      uint x0 = pk2(qacc[0][ns][0] * QSCALE, qacc[0][ns][1] * QSCALE);
      uint y0 = pk2(qacc[0][ns][2] * QSCALE, qacc[0][ns][3] * QSCALE);
      uint x1 = pk2(qacc[1][ns][0] * QSCALE, qacc[1][ns][1] * QSCALE);
      uint y1 = pk2(qacc[1][ns][2] * QSCALE, qacc[1][ns][3] * QSCALE);
      uint qa, qb, qc, qd2;
      quadx(x0, x1, qa, qb);
      quadx(y0, y1, qc, qd2);
      uint4 qw4 = make_uint4(qa, qc, qb, qd2);
      qf[ns] = __builtin_bit_cast(f16x8, qw4);
    }
  }

  // ---- Pass G (mat 3): accumulate, sigmoid, fp16-pack (16 dwords) ----
  uint2 gf[2][4];
  {
    f32x4 gacc[2][4] = {};
    #pragma unroll
    for (int kb = 0; kb < 8; ++kb) {
      f16x8 xb[4];
      #pragma unroll
      for (int nt = 0; nt < 4; ++nt)
        xb[nt] = *(const f16x8*)(xr0 + (size_t)nt * 16 * 65536 + kb * 32);
      f16x8 wg[2];
      #pragma unroll
      for (int mt = 0; mt < 2; ++mt)
        wg[mt] = *(const f16x8*)(wr0 + (size_t)3 * 65536 + mt * 4096 + kb * 32);
      #pragma unroll
      for (int mt = 0; mt < 2; ++mt)
        #pragma unroll
        for (int nt = 0; nt < 4; ++nt)
          gacc[mt][nt] = __builtin_amdgcn_mfma_f32_16x16x32_f16(wg[mt], xb[nt], gacc[mt][nt], 0, 0, 0);
    }
    #pragma unroll
    for (int mt = 0; mt < 2; ++mt) {
      float4 bgv = *(const float4*)(bg + h * 32 + mt * 16 + quad * 4);
      #pragma unroll
      for (int nt = 0; nt < 4; ++nt) {
        float g0 = 1.0f / (1.0f + __expf(-(gacc[mt][nt][0] + bgv.x)));
        float g1 = 1.0f / (1.0f + __expf(-(gacc[mt][nt][1] + bgv.y)));
        float g2 = 1.0f / (1.0f + __expf(-(gacc[mt][nt][2] + bgv.z)));
        float g3 = 1.0f / (1.0f + __expf(-(gacc[mt][nt][3] + bgv.w)));
        gf[mt][nt] = make_uint2(pk2(g0, g1), pk2(g2, g3));
      }
    }
  }

  __syncthreads();   // K/V visible (only cross-wave data)

  // ---- attention chunk loop; P stays in registers (permlane shuffle) ----
  f32x4 oacc[2][4] = {};
  float lpart[4] = {};
  #pragma unroll 1
  for (int c = 0; c < 4; ++c) {
    const int t0 = c * 64;
    #pragma unroll
    for (int half = 0; half < 2; ++half) {
      f16x8 kf0 = *(const f16x8*)&Kls[t0 + (half * 2 + 0) * 16 + lr][quad * 8];
      f16x8 kf1 = *(const f16x8*)&Kls[t0 + (half * 2 + 1) * 16 + lr][quad * 8];
      const int tq = t0 + half * 32 + quad * 8;
      f16x8 v0 = *(const f16x8*)&Vth[lr][tq];
      f16x8 v1 = *(const f16x8*)&Vth[16 + lr][tq];
      #pragma unroll
      for (int ns = 0; ns < 4; ++ns) {
        f32x4 s0 = {}, s1 = {};
        s0 = __builtin_amdgcn_mfma_f32_16x16x32_f16(kf0, qf[ns], s0, 0, 0, 0);
        s1 = __builtin_amdgcn_mfma_f32_16x16x32_f16(kf1, qf[ns], s1, 0, 0, 0);
        float e00 = exp2f(s0[0]), e01 = exp2f(s0[1]);
        float e02 = exp2f(s0[2]), e03 = exp2f(s0[3]);
        float e10 = exp2f(s1[0]), e11 = exp2f(s1[1]);
        float e12 = exp2f(s1[2]), e13 = exp2f(s1[3]);
        lpart[ns] += ((e00 + e01) + (e02 + e03)) + ((e10 + e11) + (e12 + e13));
        uint x0 = pkrtz(e00, e01), y0 = pkrtz(e02, e03);
        uint x1 = pkrtz(e10, e11), y1 = pkrtz(e12, e13);
        uint pa, pb, pc, pd;
        quadx(x0, x1, pa, pb);
        quadx(y0, y1, pc, pd);
        uint4 pw4 = make_uint4(pa, pc, pb, pd);
        f16x8 pf = __builtin_bit_cast(f16x8, pw4);
        __builtin_amdgcn_s_setprio(1);
        oacc[0][ns] = __builtin_amdgcn_mfma_f32_16x16x32_f16(v0, pf, oacc[0][ns], 0, 0, 0);
        oacc[1][ns] = __builtin_amdgcn_mfma_f32_16x16x32_f16(v1, pf, oacc[1][ns], 0, 0, 0);
        __builtin_amdgcn_s_setprio(0);
      }
    }
  }

  float invl[4];
  #pragma unroll
  for (int ns = 0; ns < 4; ++ns) {
    float v = lpart[ns];
    v += __shfl_xor(v, 16);
    v += __shfl_xor(v, 32);
    invl[ns] = 1.0f / v;
  }

  // ---- epilogue: gate from packed fp16, write O fp16 (i,h,s,d) ----
  #pragma unroll
  for (int ns = 0; ns < 4; ++ns) {
    const int s = s_base + ns * 16 + lr;
    #pragma unroll
    for (int md = 0; md < 2; ++md) {
      const int d0 = md * 16 + quad * 4;
      const uint2 g2 = gf[md][ns];
      ushort4 ov;
      ov.x = f2h(h2f((ushort)(g2.x & 0xffff))  * oacc[md][ns][0] * invl[ns]);
      ov.y = f2h(h2f((ushort)(g2.x >> 16))     * oacc[md][ns][1] * invl[ns]);
      ov.z = f2h(h2f((ushort)(g2.y & 0xffff))  * oacc[md][ns][2] * invl[ns]);
      ov.w = f2h(h2f((ushort)(g2.y >> 16))     * oacc[md][ns][3] * invl[ns]);
      *(ushort4*)(Oh + hbase + (size_t)s * HEAD_DIM + d0) = ov;
    }
  }
}

// ---------------------------------------------------------------------------
// out: pure fp16 GEMM (unchanged). A = O fp16 (i,h,s,d);
// B = Wo^T fp16 [n][k]. m-tile = (s fixed, 128 i's); BK=64 = two heads/iter.
// ---------------------------------------------------------------------------
__global__ __launch_bounds__(256) void out_kernel(
    const ushort* __restrict__ Oh, const ushort* __restrict__ Woh,
    const float* __restrict__ bo, float* __restrict__ out) {
  __shared__ __align__(16) ushort At0[128 * 32];
  __shared__ __align__(16) ushort At1[128 * 32];
  __shared__ __align__(16) ushort Bt0[128 * 32];
  __shared__ __align__(16) ushort Bt1[128 * 32];

  const int bid = blockIdx.x;                    // 0..1023
  const int xcd = bid & 7;
  const int j   = bid >> 3;                      // 0..127
  const int ntile = j & 1;
  const int rg    = (xcd << 6) + (j >> 1);       // 0..511
  const int n0 = ntile * 128;
  const int s  = rg >> 1;
  const int i0 = (rg & 1) * 128;
  const int tid = threadIdx.x;
  const int wave = tid >> 6, lane = tid & 63;
  const int wm = wave >> 1, wn = wave & 1;
  const int lr = lane & 15, quad = lane >> 4;
  const int fsw = (quad ^ ((lr >> 1) & 3)) * 8;

  const int slot = wave * 64 + lane;
  const int row0 = slot >> 2;
  const int kc   = ((slot & 3) ^ ((row0 >> 1) & 3)) * 8;

  const ushort* pA = Oh + (size_t)(i0 + row0) * 65536 + (size_t)s * 32 + kc;
  const ushort* pB = Woh + (size_t)(n0 + row0) * 256 + kc;
  const int ld0 = wave * 512;
  const int ld1 = 2048 + wave * 512;

  f32x4 acc[4][4] = {};

  for (int kk = 0; kk < 4; ++kk) {
    __syncthreads();
    gl16(pA,               At0 + ld0); gl16(pA + (size_t)64 * 65536,        At0 + ld1);
    gl16(pA + 8192,        At1 + ld0); gl16(pA + (size_t)64 * 65536 + 8192, At1 + ld1);
    gl16(pB,               Bt0 + ld0); gl16(pB + 64 * 256,                  Bt0 + ld1);
    gl16(pB + 32,          Bt1 + ld0); gl16(pB + 64 * 256 + 32,             Bt1 + ld1);
    pA += 16384;                                  // next head pair
    pB += 64;
    __syncthreads();

    f16x8 a0[4], a1[4], b0[4], b1[4];
    #pragma unroll
    for (int mt = 0; mt < 4; ++mt) {
      const int off = (wm * 64 + mt * 16 + lr) * 32 + fsw;
      a0[mt] = *(const f16x8*)&At0[off];
      a1[mt] = *(const f16x8*)&At1[off];
    }
    #pragma unroll
    for (int nt = 0; nt < 4; ++nt) {
      const int off = (wn * 64 + nt * 16 + lr) * 32 + fsw;
      b0[nt] = *(const f16x8*)&Bt0[off];
      b1[nt] = *(const f16x8*)&Bt1[off];
    }
    #pragma unroll
    for (int mt = 0; mt < 4; ++mt)
      #pragma unroll
      for (int nt = 0; nt < 4; ++nt) {
        acc[mt][nt] = __builtin_amdgcn_mfma_f32_16x16x32_f16(a0[mt], b0[nt], acc[mt][nt], 0, 0, 0);
        acc[mt][nt] = __builtin_amdgcn_mfma_f32_16x16x32_f16(a1[mt], b1[nt], acc[mt][nt], 0, 0, 0);
      }
  }

  #pragma unroll
  for (int nt = 0; nt < 4; ++nt) {
    const int col = n0 + wn * 64 + nt * 16 + lr;
    const float b = bo[col];
    #pragma unroll
    for (int mt = 0; mt < 4; ++mt)
      #pragma unroll
      for (int reg = 0; reg < 4; ++reg) {
        const int mloc = wm * 64 + mt * 16 + quad * 4 + reg;
        out[((size_t)s * 256 + i0 + mloc) * C_S + col] = acc[mt][nt][reg] + b;
      }
  }
}

// ---------------------------------------------------------------------------
extern "C" void kernel_launch(void* const* d_in, const int* in_sizes, int n_in,
                              void* d_out, int out_size, void* d_ws, size_t ws_size,
                              hipStream_t stream) {
  const float* msa   = (const float*)d_in[0];
  const float* gamma = (const float*)d_in[1];
  const float* beta  = (const float*)d_in[2];
  const float* Wq    = (const float*)d_in[3];
  const float* Wk    = (const float*)d_in[4];
  const float* Wv    = (const float*)d_in[5];
  const float* Wg    = (const float*)d_in[6];
  const float* bg    = (const float*)d_in[7];
  const float* Wo    = (const float*)d_in[8];
  const float* bo    = (const float*)d_in[9];
  float* out = (float*)d_out;

  const size_t PLANE = (size_t)NROWS * TOTAL;    // 16.78M elements
  // ws: O fp16 (33.5 MB) + W fp16 (0.66 MB)
  ushort* Oh  = (ushort*)d_ws;                   // (i,h,s,d)
  ushort* Wch = Oh + PLANE;                      // [1024][256]
  ushort* Woh = Wch + 1024 * 256;                // [256][256]
  // X fp16 lives in d_out (33.5 MB of 67 MB, dead before out_kernel writes)
  ushort* Xh = (ushort*)d_out;

  prep_w_kernel<<<1280, 256, 0, stream>>>(Wq, Wk, Wv, Wg, Wo, Wch, Woh);
  prep_x_kernel<<<NROWS / 4, 256, 0, stream>>>(msa, gamma, beta, Xh);
  fused_attn_kernel<<<I_DIM * NUM_HEADS, 256, 0, stream>>>(Xh, Wch, bg, Oh);
  out_kernel<<<1024, 256, 0, stream>>>(Oh, Woh, bo, out);
}

// Round 7
// 289.846 us; speedup vs baseline: 1.2198x; 1.2198x over previous
//
#include <hip/hip_runtime.h>
#include <hip/hip_fp16.h>
#include <math.h>

#define C_S 256
#define NUM_HEADS 8
#define HEAD_DIM 32
#define TOTAL 256
#define S_DIM 256
#define I_DIM 256
#define NROWS (S_DIM * I_DIM)   // 65536
#define LN_EPS 1e-5f
#define QSCALE 0.25503534f      // log2(e)/sqrt(32)

typedef _Float16 f16x8 __attribute__((ext_vector_type(8)));   // 8 fp16 = 4 VGPR
typedef __attribute__((ext_vector_type(4))) float f32x4;

__device__ __forceinline__ ushort f2h(float x) {
  return __half_as_ushort(__float2half(x));      // RNE
}
__device__ __forceinline__ float h2f(ushort u) {
  return __half2float(__ushort_as_half(u));
}
// pack two f32 -> two fp16 (RTZ) in one VALU op; returns the 32-bit word
__device__ __forceinline__ uint pkrtz(float a, float b) {
  return __builtin_bit_cast(uint, __builtin_amdgcn_cvt_pkrtz(a, b));
}
// async global->LDS, 16B per lane; lds base must be wave-uniform.
__device__ __forceinline__ void gl16(const void* g, void* l) {
  __builtin_amdgcn_global_load_lds(
      (const __attribute__((address_space(1))) unsigned*)g,
      (__attribute__((address_space(3))) unsigned*)l, 16, 0, 0);
}
// quad all-to-all within same lr: inputs (x0 = block0 dword, x1 = block1 dword)
// outputs: o0 = dword for src-quads {2(q&1)}, o1 = for {2(q&1)+1}, block q>>1.
__device__ __forceinline__ void quadx(uint x0, uint x1, uint& o0, uint& o1) {
  auto a = __builtin_amdgcn_permlane32_swap(x0, x1, false, false);
  auto b = __builtin_amdgcn_permlane16_swap(a[0], a[1], false, false);
  o0 = b[0]; o1 = b[1];
}

// ---------------------------------------------------------------------------
// prep_w: transpose + fp16-convert weights once.
// QKVG -> combined [1024][256] fp16 (row = mat*256+n, k contiguous);
// Wo -> [256][256] fp16.
// ---------------------------------------------------------------------------
__global__ __launch_bounds__(256) void prep_w_kernel(
    const float* __restrict__ Wq, const float* __restrict__ Wk,
    const float* __restrict__ Wv, const float* __restrict__ Wg,
    const float* __restrict__ Wo,
    ushort* __restrict__ Wch, ushort* __restrict__ Woh) {
  const int b = blockIdx.x;            // 0..1279
  const int mat = b >> 8, n = b & 255;
  const int k = threadIdx.x;
  const float* W = (mat == 0) ? Wq : (mat == 1) ? Wk
                  : (mat == 2) ? Wv : (mat == 3) ? Wg : Wo;
  ushort h = f2h(W[(size_t)k * 256 + n]);
  if (mat < 4) Wch[((size_t)(mat * 256 + n)) * 256 + k] = h;
  else         Woh[(size_t)n * 256 + k] = h;
}

// ---------------------------------------------------------------------------
// prep_x: LN stats + apply + fp16-convert, once. One wave per row.
// X fp16 lives in d_out first half (dead until out_kernel overwrites it).
// ---------------------------------------------------------------------------
__global__ __launch_bounds__(256) void prep_x_kernel(
    const float* __restrict__ msa, const float* __restrict__ gamma,
    const float* __restrict__ beta, ushort* __restrict__ Xh) {
  const int row  = blockIdx.x * 4 + (threadIdx.x >> 6);
  const int lane = threadIdx.x & 63;
  float4 v = ((const float4*)(msa + (size_t)row * C_S))[lane];
  float sum = v.x + v.y + v.z + v.w;
  float sq  = v.x*v.x + v.y*v.y + v.z*v.z + v.w*v.w;
  #pragma unroll
  for (int off = 1; off < 64; off <<= 1) {
    sum += __shfl_xor(sum, off);
    sq  += __shfl_xor(sq, off);
  }
  float mu = sum * (1.0f / 256.0f);
  float rs = rsqrtf(sq * (1.0f / 256.0f) - mu * mu + LN_EPS);
  float4 gv = ((const float4*)gamma)[lane];
  float4 bv = ((const float4*)beta)[lane];
  ushort4 hh;
  hh.x = f2h((v.x - mu) * rs * gv.x + bv.x);
  hh.y = f2h((v.y - mu) * rs * gv.y + bv.y);
  hh.z = f2h((v.z - mu) * rs * gv.z + bv.z);
  hh.w = f2h((v.w - mu) * rs * gv.w + bv.w);
  *(ushort4*)(Xh + (size_t)row * 256 + lane * 4) = hh;
}

// ---------------------------------------------------------------------------
// fused_attn: one block per (i,h). 256 threads / 4 waves; wave owns 64 rows.
//  LDS 36.5 KB (4 blocks/CU by LDS):
//   Kls[256][40]  K[t][d]                                       20.0 KB
//   Vth[32][264]  V^T[d][t]  (filled by swapped-operand MFMA)   16.5 KB
//  Structure = R5 champion (142 us), ONE mechanism changed:
//   GATE OFFLOAD: G (cold, epilogue-only) no longer rides the chunk loop
//   in 32 AGPRs. Phase B applies bias+sigmoid, packs fp16, stores each
//   lane's own 32B to Gh (global, second half of d_out); epilogue reloads
//   the same addresses (same block -> L2-local). Loop-carried set drops to
//   qf16 + oacc32(AGPR) + temps ~= 92 regs -> (256,4)'s 128-reg budget
//   finally FITS (R4/R6 lesson: asking for 4 waves/EU with a >128 live set
//   just makes the allocator split 64/64 and thrash scratch).
//  Per-iteration s_setprio removed (64 toggles/loop; lockstep-structure
//  null per m190; frees scheduler to interleave the 4 independent ns
//  chains). P stays in registers via permlane quad-exchange.
//  Falsifier: VGPR_Count=64 + WRITE_SIZE >> 70MB -> spill returned.
// ---------------------------------------------------------------------------
__global__ __launch_bounds__(256, 4) void fused_attn_kernel(
    const ushort* __restrict__ Xh,    // [65536][256], row = s*256+i
    const ushort* __restrict__ Wch,   // [1024][256], row = mat*256+n
    const float* __restrict__ bg,
    ushort* __restrict__ Oh,          // (i,h,s,d) fp16
    ushort* __restrict__ Gh) {        // (i,h,s,d) fp16 gate scratch
  __shared__ __align__(16) ushort Kls[256][40];   // 20.0 KB  K[t][d]
  __shared__ __align__(16) ushort Vth[32][264];   // 16.5 KB  V^T[d][t]

  const int bid = blockIdx.x;
  const int xcd = bid & 7, j = bid >> 3;
  const int h = j & 7;
  const int i = (xcd << 5) + (j >> 3);            // 32 consecutive i per XCD
  const int ih = i * NUM_HEADS + h;
  const int tid = threadIdx.x;
  const int wave = tid >> 6, lane = tid & 63;
  const int lr = lane & 15, quad = lane >> 4;
  const int s_base = wave * 64;
  const size_t hbase = (size_t)ih * (S_DIM * HEAD_DIM);

  // X B-frag base: row (s,i) = (s*256+i), element quad*8 within k-chunk
  const ushort* xr0 = Xh + ((size_t)(s_base + lr) * 256 + i) * 256 + quad * 8;
  // W^T A-frag base: row = mat*256 + h*32 + (mt*16+lr)
  const ushort* wr0 = Wch + ((size_t)(h * 32 + lr)) * 256 + quad * 8;

  // ---- Phase A: K^T (mat 1), V^T (mat 2, swapped operands) ----
  {
    f32x4 kacc[2][4] = {}, vacc[2][4] = {};
    #pragma unroll
    for (int kb = 0; kb < 8; ++kb) {
      f16x8 xb[4];
      #pragma unroll
      for (int nt = 0; nt < 4; ++nt)
        xb[nt] = *(const f16x8*)(xr0 + (size_t)nt * 16 * 65536 + kb * 32);
      f16x8 wk[2], wv[2];
      #pragma unroll
      for (int mt = 0; mt < 2; ++mt) {
        wk[mt] = *(const f16x8*)(wr0 + (size_t)1 * 65536 + mt * 4096 + kb * 32);
        wv[mt] = *(const f16x8*)(wr0 + (size_t)2 * 65536 + mt * 4096 + kb * 32);
      }
      #pragma unroll
      for (int mt = 0; mt < 2; ++mt)
        #pragma unroll
        for (int nt = 0; nt < 4; ++nt) {
          kacc[mt][nt] = __builtin_amdgcn_mfma_f32_16x16x32_f16(wk[mt], xb[nt], kacc[mt][nt], 0, 0, 0);
          // swapped: D col = d (lr), row = t (quad*4+reg) -> packed V^T store
          vacc[mt][nt] = __builtin_amdgcn_mfma_f32_16x16x32_f16(xb[nt], wv[mt], vacc[mt][nt], 0, 0, 0);
        }
    }
    #pragma unroll
    for (int mt = 0; mt < 2; ++mt)
      #pragma unroll
      for (int nt = 0; nt < 4; ++nt) {
        // K: D col = t (nt*16+lr), row = d (mt*16+quad*4+reg)
        const int t = s_base + nt * 16 + lr;
        ushort4 kp;
        kp.x = f2h(kacc[mt][nt][0]); kp.y = f2h(kacc[mt][nt][1]);
        kp.z = f2h(kacc[mt][nt][2]); kp.w = f2h(kacc[mt][nt][3]);
        *(ushort4*)&Kls[t][mt * 16 + quad * 4] = kp;
        // V (swapped): lane holds V^T[d = mt*16+lr][t = s_base+nt*16+quad*4+reg]
        ushort4 vp;
        vp.x = f2h(vacc[mt][nt][0]); vp.y = f2h(vacc[mt][nt][1]);
        vp.z = f2h(vacc[mt][nt][2]); vp.w = f2h(vacc[mt][nt][3]);
        *(ushort4*)&Vth[mt * 16 + lr][s_base + nt * 16 + quad * 4] = vp;
      }
  }

  // ---- Phase B: Q^T (mat 0), G^T (mat 3) ----
  f16x8 qf[4];
  {
    f32x4 qacc[2][4] = {}, gacc[2][4] = {};
    #pragma unroll
    for (int kb = 0; kb < 8; ++kb) {
      f16x8 xb[4];
      #pragma unroll
      for (int nt = 0; nt < 4; ++nt)
        xb[nt] = *(const f16x8*)(xr0 + (size_t)nt * 16 * 65536 + kb * 32);
      f16x8 wq[2], wg[2];
      #pragma unroll
      for (int mt = 0; mt < 2; ++mt) {
        wq[mt] = *(const f16x8*)(wr0 + (size_t)0 * 65536 + mt * 4096 + kb * 32);
        wg[mt] = *(const f16x8*)(wr0 + (size_t)3 * 65536 + mt * 4096 + kb * 32);
      }
      #pragma unroll
      for (int mt = 0; mt < 2; ++mt)
        #pragma unroll
        for (int nt = 0; nt < 4; ++nt) {
          qacc[mt][nt] = __builtin_amdgcn_mfma_f32_16x16x32_f16(wq[mt], xb[nt], qacc[mt][nt], 0, 0, 0);
          gacc[mt][nt] = __builtin_amdgcn_mfma_f32_16x16x32_f16(wg[mt], xb[nt], gacc[mt][nt], 0, 0, 0);
        }
    }
    // G: bias+sigmoid, fp16 pack, OFFLOAD to global (cold until epilogue).
    // Lane stores its own (s,d0) ushort4; epilogue reloads same address.
    #pragma unroll
    for (int mt = 0; mt < 2; ++mt) {
      const int d0 = mt * 16 + quad * 4;
      float4 bgv = *(const float4*)(bg + h * 32 + d0);
      #pragma unroll
      for (int nt = 0; nt < 4; ++nt) {
        const int s = s_base + nt * 16 + lr;
        ushort4 gp;
        gp.x = f2h(1.0f / (1.0f + __expf(-(gacc[mt][nt][0] + bgv.x))));
        gp.y = f2h(1.0f / (1.0f + __expf(-(gacc[mt][nt][1] + bgv.y))));
        gp.z = f2h(1.0f / (1.0f + __expf(-(gacc[mt][nt][2] + bgv.z))));
        gp.w = f2h(1.0f / (1.0f + __expf(-(gacc[mt][nt][3] + bgv.w))));
        *(ushort4*)(Gh + hbase + (size_t)s * HEAD_DIM + d0) = gp;
      }
    }
    // Q -> B-operand frags in registers via quad exchange (RNE pack).
    // Source: lane holds Q[d = mt*16+quad*4+reg][s = ns*16+lr].
    #pragma unroll
    for (int ns = 0; ns < 4; ++ns) {
      uint x0 = (uint)f2h(qacc[0][ns][0] * QSCALE) | ((uint)f2h(qacc[0][ns][1] * QSCALE) << 16);
      uint y0 = (uint)f2h(qacc[0][ns][2] * QSCALE) | ((uint)f2h(qacc[0][ns][3] * QSCALE) << 16);
      uint x1 = (uint)f2h(qacc[1][ns][0] * QSCALE) | ((uint)f2h(qacc[1][ns][1] * QSCALE) << 16);
      uint y1 = (uint)f2h(qacc[1][ns][2] * QSCALE) | ((uint)f2h(qacc[1][ns][3] * QSCALE) << 16);
      uint qa, qb, qc, qd2;
      quadx(x0, x1, qa, qb);
      quadx(y0, y1, qc, qd2);
      uint4 qw4 = make_uint4(qa, qc, qb, qd2);
      qf[ns] = __builtin_bit_cast(f16x8, qw4);
    }
  }

  __syncthreads();   // K/V visible (only cross-wave data)

  // ---- attention chunk loop; P stays in registers (permlane shuffle) ----
  f32x4 oacc[2][4] = {};
  float lpart[4] = {};
  #pragma unroll 1
  for (int c = 0; c < 4; ++c) {
    const int t0 = c * 64;
    #pragma unroll
    for (int half = 0; half < 2; ++half) {
      f16x8 kf0 = *(const f16x8*)&Kls[t0 + (half * 2 + 0) * 16 + lr][quad * 8];
      f16x8 kf1 = *(const f16x8*)&Kls[t0 + (half * 2 + 1) * 16 + lr][quad * 8];
      const int tq = t0 + half * 32 + quad * 8;
      f16x8 v0 = *(const f16x8*)&Vth[lr][tq];
      f16x8 v1 = *(const f16x8*)&Vth[16 + lr][tq];
      #pragma unroll
      for (int ns = 0; ns < 4; ++ns) {
        f32x4 s0 = {}, s1 = {};
        s0 = __builtin_amdgcn_mfma_f32_16x16x32_f16(kf0, qf[ns], s0, 0, 0, 0);
        s1 = __builtin_amdgcn_mfma_f32_16x16x32_f16(kf1, qf[ns], s1, 0, 0, 0);
        float e00 = exp2f(s0[0]), e01 = exp2f(s0[1]);
        float e02 = exp2f(s0[2]), e03 = exp2f(s0[3]);
        float e10 = exp2f(s1[0]), e11 = exp2f(s1[1]);
        float e12 = exp2f(s1[2]), e13 = exp2f(s1[3]);
        lpart[ns] += ((e00 + e01) + (e02 + e03)) + ((e10 + e11) + (e12 + e13));
        uint x0 = pkrtz(e00, e01), y0 = pkrtz(e02, e03);
        uint x1 = pkrtz(e10, e11), y1 = pkrtz(e12, e13);
        uint pa, pb, pc, pd;
        quadx(x0, x1, pa, pb);
        quadx(y0, y1, pc, pd);
        uint4 pw4 = make_uint4(pa, pc, pb, pd);
        f16x8 pf = __builtin_bit_cast(f16x8, pw4);
        oacc[0][ns] = __builtin_amdgcn_mfma_f32_16x16x32_f16(v0, pf, oacc[0][ns], 0, 0, 0);
        oacc[1][ns] = __builtin_amdgcn_mfma_f32_16x16x32_f16(v1, pf, oacc[1][ns], 0, 0, 0);
      }
    }
  }

  float invl[4];
  #pragma unroll
  for (int ns = 0; ns < 4; ++ns) {
    float v = lpart[ns];
    v += __shfl_xor(v, 16);
    v += __shfl_xor(v, 32);
    invl[ns] = 1.0f / v;
  }

  // ---- epilogue: reload fp16 gate, write O fp16 (i,h,s,d) ----
  #pragma unroll
  for (int ns = 0; ns < 4; ++ns) {
    const int s = s_base + ns * 16 + lr;
    #pragma unroll
    for (int md = 0; md < 2; ++md) {
      const int d0 = md * 16 + quad * 4;
      ushort4 g4 = *(const ushort4*)(Gh + hbase + (size_t)s * HEAD_DIM + d0);
      ushort4 ov;
      ov.x = f2h(h2f(g4.x) * oacc[md][ns][0] * invl[ns]);
      ov.y = f2h(h2f(g4.y) * oacc[md][ns][1] * invl[ns]);
      ov.z = f2h(h2f(g4.z) * oacc[md][ns][2] * invl[ns]);
      ov.w = f2h(h2f(g4.w) * oacc[md][ns][3] * invl[ns]);
      *(ushort4*)(Oh + hbase + (size_t)s * HEAD_DIM + d0) = ov;
    }
  }
}

// ---------------------------------------------------------------------------
// out: pure fp16 GEMM (unchanged). A = O fp16 (i,h,s,d);
// B = Wo^T fp16 [n][k]. m-tile = (s fixed, 128 i's); BK=64 = two heads/iter.
// ---------------------------------------------------------------------------
__global__ __launch_bounds__(256) void out_kernel(
    const ushort* __restrict__ Oh, const ushort* __restrict__ Woh,
    const float* __restrict__ bo, float* __restrict__ out) {
  __shared__ __align__(16) ushort At0[128 * 32];
  __shared__ __align__(16) ushort At1[128 * 32];
  __shared__ __align__(16) ushort Bt0[128 * 32];
  __shared__ __align__(16) ushort Bt1[128 * 32];

  const int bid = blockIdx.x;                    // 0..1023
  const int xcd = bid & 7;
  const int j   = bid >> 3;                      // 0..127
  const int ntile = j & 1;
  const int rg    = (xcd << 6) + (j >> 1);       // 0..511
  const int n0 = ntile * 128;
  const int s  = rg >> 1;
  const int i0 = (rg & 1) * 128;
  const int tid = threadIdx.x;
  const int wave = tid >> 6, lane = tid & 63;
  const int wm = wave >> 1, wn = wave & 1;
  const int lr = lane & 15, quad = lane >> 4;
  const int fsw = (quad ^ ((lr >> 1) & 3)) * 8;

  const int slot = wave * 64 + lane;
  const int row0 = slot >> 2;
  const int kc   = ((slot & 3) ^ ((row0 >> 1) & 3)) * 8;

  const ushort* pA = Oh + (size_t)(i0 + row0) * 65536 + (size_t)s * 32 + kc;
  const ushort* pB = Woh + (size_t)(n0 + row0) * 256 + kc;
  const int ld0 = wave * 512;
  const int ld1 = 2048 + wave * 512;

  f32x4 acc[4][4] = {};

  for (int kk = 0; kk < 4; ++kk) {
    __syncthreads();
    gl16(pA,               At0 + ld0); gl16(pA + (size_t)64 * 65536,        At0 + ld1);
    gl16(pA + 8192,        At1 + ld0); gl16(pA + (size_t)64 * 65536 + 8192, At1 + ld1);
    gl16(pB,               Bt0 + ld0); gl16(pB + 64 * 256,                  Bt0 + ld1);
    gl16(pB + 32,          Bt1 + ld0); gl16(pB + 64 * 256 + 32,             Bt1 + ld1);
    pA += 16384;                                  // next head pair
    pB += 64;
    __syncthreads();

    f16x8 a0[4], a1[4], b0[4], b1[4];
    #pragma unroll
    for (int mt = 0; mt < 4; ++mt) {
      const int off = (wm * 64 + mt * 16 + lr) * 32 + fsw;
      a0[mt] = *(const f16x8*)&At0[off];
      a1[mt] = *(const f16x8*)&At1[off];
    }
    #pragma unroll
    for (int nt = 0; nt < 4; ++nt) {
      const int off = (wn * 64 + nt * 16 + lr) * 32 + fsw;
      b0[nt] = *(const f16x8*)&Bt0[off];
      b1[nt] = *(const f16x8*)&Bt1[off];
    }
    #pragma unroll
    for (int mt = 0; mt < 4; ++mt)
      #pragma unroll
      for (int nt = 0; nt < 4; ++nt) {
        acc[mt][nt] = __builtin_amdgcn_mfma_f32_16x16x32_f16(a0[mt], b0[nt], acc[mt][nt], 0, 0, 0);
        acc[mt][nt] = __builtin_amdgcn_mfma_f32_16x16x32_f16(a1[mt], b1[nt], acc[mt][nt], 0, 0, 0);
      }
  }

  #pragma unroll
  for (int nt = 0; nt < 4; ++nt) {
    const int col = n0 + wn * 64 + nt * 16 + lr;
    const float b = bo[col];
    #pragma unroll
    for (int mt = 0; mt < 4; ++mt)
      #pragma unroll
      for (int reg = 0; reg < 4; ++reg) {
        const int mloc = wm * 64 + mt * 16 + quad * 4 + reg;
        out[((size_t)s * 256 + i0 + mloc) * C_S + col] = acc[mt][nt][reg] + b;
      }
  }
}

// ---------------------------------------------------------------------------
extern "C" void kernel_launch(void* const* d_in, const int* in_sizes, int n_in,
                              void* d_out, int out_size, void* d_ws, size_t ws_size,
                              hipStream_t stream) {
  const float* msa   = (const float*)d_in[0];
  const float* gamma = (const float*)d_in[1];
  const float* beta  = (const float*)d_in[2];
  const float* Wq    = (const float*)d_in[3];
  const float* Wk    = (const float*)d_in[4];
  const float* Wv    = (const float*)d_in[5];
  const float* Wg    = (const float*)d_in[6];
  const float* bg    = (const float*)d_in[7];
  const float* Wo    = (const float*)d_in[8];
  const float* bo    = (const float*)d_in[9];
  float* out = (float*)d_out;

  const size_t PLANE = (size_t)NROWS * TOTAL;    // 16.78M elements
  // ws: O fp16 (33.5 MB) + W fp16 (0.66 MB)
  ushort* Oh  = (ushort*)d_ws;                   // (i,h,s,d)
  ushort* Wch = Oh + PLANE;                      // [1024][256]
  ushort* Woh = Wch + 1024 * 256;                // [256][256]
  // d_out (67 MB) doubles as scratch before out_kernel overwrites it:
  //   first half  = X fp16, second half = G fp16 gate
  ushort* Xh = (ushort*)d_out;
  ushort* Gh = Xh + PLANE;

  prep_w_kernel<<<1280, 256, 0, stream>>>(Wq, Wk, Wv, Wg, Wo, Wch, Woh);
  prep_x_kernel<<<NROWS / 4, 256, 0, stream>>>(msa, gamma, beta, Xh);
  fused_attn_kernel<<<I_DIM * NUM_HEADS, 256, 0, stream>>>(Xh, Wch, bg, Oh, Gh);
  out_kernel<<<1024, 256, 0, stream>>>(Oh, Woh, bo, out);
}

// Round 8
// 281.764 us; speedup vs baseline: 1.2547x; 1.0287x over previous
//
#include <hip/hip_runtime.h>
#include <hip/hip_fp16.h>
#include <math.h>

#define C_S 256
#define NUM_HEADS 8
#define HEAD_DIM 32
#define TOTAL 256
#define S_DIM 256
#define I_DIM 256
#define NROWS (S_DIM * I_DIM)   // 65536
#define LN_EPS 1e-5f
#define QSCALE 0.25503534f      // log2(e)/sqrt(32)

typedef _Float16 f16x8 __attribute__((ext_vector_type(8)));   // 8 fp16 = 4 VGPR
typedef __attribute__((ext_vector_type(4))) float f32x4;

__device__ __forceinline__ ushort f2h(float x) {
  return __half_as_ushort(__float2half(x));      // RNE
}
__device__ __forceinline__ float h2f(ushort u) {
  return __half2float(__ushort_as_half(u));
}
// pack two f32 -> two fp16 (RTZ) in one VALU op; returns the 32-bit word
__device__ __forceinline__ uint pkrtz(float a, float b) {
  return __builtin_bit_cast(uint, __builtin_amdgcn_cvt_pkrtz(a, b));
}
// async global->LDS, 16B per lane; lds base must be wave-uniform.
__device__ __forceinline__ void gl16(const void* g, void* l) {
  __builtin_amdgcn_global_load_lds(
      (const __attribute__((address_space(1))) unsigned*)g,
      (__attribute__((address_space(3))) unsigned*)l, 16, 0, 0);
}
// quad all-to-all within same lr: inputs (x0 = block0 dword, x1 = block1 dword)
// outputs: o0 = dword for src-quads {2(q&1)}, o1 = for {2(q&1)+1}, block q>>1.
__device__ __forceinline__ void quadx(uint x0, uint x1, uint& o0, uint& o1) {
  auto a = __builtin_amdgcn_permlane32_swap(x0, x1, false, false);
  auto b = __builtin_amdgcn_permlane16_swap(a[0], a[1], false, false);
  o0 = b[0]; o1 = b[1];
}

// ---------------------------------------------------------------------------
// prep_w: transpose + fp16-convert weights once.
// QKVG -> combined [1024][256] fp16 (row = mat*256+n, k contiguous);
// Wo -> [256][256] fp16.
// ---------------------------------------------------------------------------
__global__ __launch_bounds__(256) void prep_w_kernel(
    const float* __restrict__ Wq, const float* __restrict__ Wk,
    const float* __restrict__ Wv, const float* __restrict__ Wg,
    const float* __restrict__ Wo,
    ushort* __restrict__ Wch, ushort* __restrict__ Woh) {
  const int b = blockIdx.x;            // 0..1279
  const int mat = b >> 8, n = b & 255;
  const int k = threadIdx.x;
  const float* W = (mat == 0) ? Wq : (mat == 1) ? Wk
                  : (mat == 2) ? Wv : (mat == 3) ? Wg : Wo;
  ushort h = f2h(W[(size_t)k * 256 + n]);
  if (mat < 4) Wch[((size_t)(mat * 256 + n)) * 256 + k] = h;
  else         Woh[(size_t)n * 256 + k] = h;
}

// ---------------------------------------------------------------------------
// prep_x: LN stats + apply + fp16-convert, once. One wave per row.
// X fp16 lives in d_out (dead until out_kernel overwrites it).
// ---------------------------------------------------------------------------
__global__ __launch_bounds__(256) void prep_x_kernel(
    const float* __restrict__ msa, const float* __restrict__ gamma,
    const float* __restrict__ beta, ushort* __restrict__ Xh) {
  const int row  = blockIdx.x * 4 + (threadIdx.x >> 6);
  const int lane = threadIdx.x & 63;
  float4 v = ((const float4*)(msa + (size_t)row * C_S))[lane];
  float sum = v.x + v.y + v.z + v.w;
  float sq  = v.x*v.x + v.y*v.y + v.z*v.z + v.w*v.w;
  #pragma unroll
  for (int off = 1; off < 64; off <<= 1) {
    sum += __shfl_xor(sum, off);
    sq  += __shfl_xor(sq, off);
  }
  float mu = sum * (1.0f / 256.0f);
  float rs = rsqrtf(sq * (1.0f / 256.0f) - mu * mu + LN_EPS);
  float4 gv = ((const float4*)gamma)[lane];
  float4 bv = ((const float4*)beta)[lane];
  ushort4 hh;
  hh.x = f2h((v.x - mu) * rs * gv.x + bv.x);
  hh.y = f2h((v.y - mu) * rs * gv.y + bv.y);
  hh.z = f2h((v.z - mu) * rs * gv.z + bv.z);
  hh.w = f2h((v.w - mu) * rs * gv.w + bv.w);
  *(ushort4*)(Xh + (size_t)row * 256 + lane * 4) = hh;
}

// ---------------------------------------------------------------------------
// fused_attn: R5 champion, unchanged (142.4 us, VGPR 84, no spill).
// one block per (i,h); 256 threads / 4 waves; wave owns 64 rows.
//  LDS 36.5 KB: Kls[256][40] K[t][d] + Vth[32][264] V^T[d][t].
//  P never touches LDS (permlane quad-exchange); gacc rides AGPRs to the
//  epilogue. (256,3): 170-reg unified budget >= ~130 live set -> no spill.
//  CLOSED: (256,4) tried 3x (R4/R6/R7) -> allocator splits 64/64 and
//  spills ~0.1-0.5 GB scratch every time. Do not retry.
// ---------------------------------------------------------------------------
__global__ __launch_bounds__(256, 3) void fused_attn_kernel(
    const ushort* __restrict__ Xh,    // [65536][256], row = s*256+i
    const ushort* __restrict__ Wch,   // [1024][256], row = mat*256+n
    const float* __restrict__ bg,
    ushort* __restrict__ Oh) {        // (i,h,s,d) fp16
  __shared__ __align__(16) ushort Kls[256][40];   // 20.0 KB  K[t][d]
  __shared__ __align__(16) ushort Vth[32][264];   // 16.5 KB  V^T[d][t]

  const int bid = blockIdx.x;
  const int xcd = bid & 7, j = bid >> 3;
  const int h = j & 7;
  const int i = (xcd << 5) + (j >> 3);            // 32 consecutive i per XCD
  const int ih = i * NUM_HEADS + h;
  const int tid = threadIdx.x;
  const int wave = tid >> 6, lane = tid & 63;
  const int lr = lane & 15, quad = lane >> 4;
  const int s_base = wave * 64;
  const size_t hbase = (size_t)ih * (S_DIM * HEAD_DIM);

  // X B-frag base: row (s,i) = (s*256+i), element quad*8 within k-chunk
  const ushort* xr0 = Xh + ((size_t)(s_base + lr) * 256 + i) * 256 + quad * 8;
  // W^T A-frag base: row = mat*256 + h*32 + (mt*16+lr)
  const ushort* wr0 = Wch + ((size_t)(h * 32 + lr)) * 256 + quad * 8;

  // ---- Phase A: K^T (mat 1), V^T (mat 2, swapped operands) ----
  f32x4 kacc[2][4] = {}, vacc[2][4] = {};
  #pragma unroll
  for (int kb = 0; kb < 8; ++kb) {
    f16x8 xb[4];
    #pragma unroll
    for (int nt = 0; nt < 4; ++nt)
      xb[nt] = *(const f16x8*)(xr0 + (size_t)nt * 16 * 65536 + kb * 32);
    f16x8 wk[2], wv[2];
    #pragma unroll
    for (int mt = 0; mt < 2; ++mt) {
      wk[mt] = *(const f16x8*)(wr0 + (size_t)1 * 65536 + mt * 4096 + kb * 32);
      wv[mt] = *(const f16x8*)(wr0 + (size_t)2 * 65536 + mt * 4096 + kb * 32);
    }
    #pragma unroll
    for (int mt = 0; mt < 2; ++mt)
      #pragma unroll
      for (int nt = 0; nt < 4; ++nt) {
        kacc[mt][nt] = __builtin_amdgcn_mfma_f32_16x16x32_f16(wk[mt], xb[nt], kacc[mt][nt], 0, 0, 0);
        // swapped: D col = d (lr), row = t (quad*4+reg) -> packed V^T store
        vacc[mt][nt] = __builtin_amdgcn_mfma_f32_16x16x32_f16(xb[nt], wv[mt], vacc[mt][nt], 0, 0, 0);
      }
  }
  #pragma unroll
  for (int mt = 0; mt < 2; ++mt)
    #pragma unroll
    for (int nt = 0; nt < 4; ++nt) {
      // K: D col = t (nt*16+lr), row = d (mt*16+quad*4+reg)
      const int t = s_base + nt * 16 + lr;
      ushort4 kp;
      kp.x = f2h(kacc[mt][nt][0]); kp.y = f2h(kacc[mt][nt][1]);
      kp.z = f2h(kacc[mt][nt][2]); kp.w = f2h(kacc[mt][nt][3]);
      *(ushort4*)&Kls[t][mt * 16 + quad * 4] = kp;
      // V (swapped): lane holds V^T[d = mt*16+lr][t = s_base+nt*16+quad*4+reg]
      ushort4 vp;
      vp.x = f2h(vacc[mt][nt][0]); vp.y = f2h(vacc[mt][nt][1]);
      vp.z = f2h(vacc[mt][nt][2]); vp.w = f2h(vacc[mt][nt][3]);
      *(ushort4*)&Vth[mt * 16 + lr][s_base + nt * 16 + quad * 4] = vp;
    }

  // ---- Phase B: Q^T (mat 0), G^T (mat 3) ----
  f32x4 qacc[2][4] = {}, gacc[2][4] = {};
  #pragma unroll
  for (int kb = 0; kb < 8; ++kb) {
    f16x8 xb[4];
    #pragma unroll
    for (int nt = 0; nt < 4; ++nt)
      xb[nt] = *(const f16x8*)(xr0 + (size_t)nt * 16 * 65536 + kb * 32);
    f16x8 wq[2], wg[2];
    #pragma unroll
    for (int mt = 0; mt < 2; ++mt) {
      wq[mt] = *(const f16x8*)(wr0 + (size_t)0 * 65536 + mt * 4096 + kb * 32);
      wg[mt] = *(const f16x8*)(wr0 + (size_t)3 * 65536 + mt * 4096 + kb * 32);
    }
    #pragma unroll
    for (int mt = 0; mt < 2; ++mt)
      #pragma unroll
      for (int nt = 0; nt < 4; ++nt) {
        qacc[mt][nt] = __builtin_amdgcn_mfma_f32_16x16x32_f16(wq[mt], xb[nt], qacc[mt][nt], 0, 0, 0);
        gacc[mt][nt] = __builtin_amdgcn_mfma_f32_16x16x32_f16(wg[mt], xb[nt], gacc[mt][nt], 0, 0, 0);
      }
  }
  // Q -> B-operand frags purely in registers via quad exchange (RNE pack).
  f16x8 qf[4];
  #pragma unroll
  for (int ns = 0; ns < 4; ++ns) {
    uint x0 = (uint)f2h(qacc[0][ns][0] * QSCALE) | ((uint)f2h(qacc[0][ns][1] * QSCALE) << 16);
    uint y0 = (uint)f2h(qacc[0][ns][2] * QSCALE) | ((uint)f2h(qacc[0][ns][3] * QSCALE) << 16);
    uint x1 = (uint)f2h(qacc[1][ns][0] * QSCALE) | ((uint)f2h(qacc[1][ns][1] * QSCALE) << 16);
    uint y1 = (uint)f2h(qacc[1][ns][2] * QSCALE) | ((uint)f2h(qacc[1][ns][3] * QSCALE) << 16);
    uint qa, qb, qc, qd2;
    quadx(x0, x1, qa, qb);
    quadx(y0, y1, qc, qd2);
    uint4 qw4 = make_uint4(qa, qc, qb, qd2);
    qf[ns] = __builtin_bit_cast(f16x8, qw4);
  }

  __syncthreads();   // K/V visible (only cross-wave data)

  // ---- attention chunk loop; P stays in registers (permlane shuffle) ----
  f32x4 oacc[2][4] = {};
  float lpart[4] = {};
  #pragma unroll 1
  for (int c = 0; c < 4; ++c) {
    const int t0 = c * 64;
    #pragma unroll
    for (int half = 0; half < 2; ++half) {
      f16x8 kf0 = *(const f16x8*)&Kls[t0 + (half * 2 + 0) * 16 + lr][quad * 8];
      f16x8 kf1 = *(const f16x8*)&Kls[t0 + (half * 2 + 1) * 16 + lr][quad * 8];
      const int tq = t0 + half * 32 + quad * 8;
      f16x8 v0 = *(const f16x8*)&Vth[lr][tq];
      f16x8 v1 = *(const f16x8*)&Vth[16 + lr][tq];
      #pragma unroll
      for (int ns = 0; ns < 4; ++ns) {
        f32x4 s0 = {}, s1 = {};
        s0 = __builtin_amdgcn_mfma_f32_16x16x32_f16(kf0, qf[ns], s0, 0, 0, 0);
        s1 = __builtin_amdgcn_mfma_f32_16x16x32_f16(kf1, qf[ns], s1, 0, 0, 0);
        float e00 = exp2f(s0[0]), e01 = exp2f(s0[1]);
        float e02 = exp2f(s0[2]), e03 = exp2f(s0[3]);
        float e10 = exp2f(s1[0]), e11 = exp2f(s1[1]);
        float e12 = exp2f(s1[2]), e13 = exp2f(s1[3]);
        lpart[ns] += ((e00 + e01) + (e02 + e03)) + ((e10 + e11) + (e12 + e13));
        uint x0 = pkrtz(e00, e01), y0 = pkrtz(e02, e03);
        uint x1 = pkrtz(e10, e11), y1 = pkrtz(e12, e13);
        uint pa, pb, pc, pd;
        quadx(x0, x1, pa, pb);
        quadx(y0, y1, pc, pd);
        uint4 pw4 = make_uint4(pa, pc, pb, pd);
        f16x8 pf = __builtin_bit_cast(f16x8, pw4);
        __builtin_amdgcn_s_setprio(1);
        oacc[0][ns] = __builtin_amdgcn_mfma_f32_16x16x32_f16(v0, pf, oacc[0][ns], 0, 0, 0);
        oacc[1][ns] = __builtin_amdgcn_mfma_f32_16x16x32_f16(v1, pf, oacc[1][ns], 0, 0, 0);
        __builtin_amdgcn_s_setprio(0);
      }
    }
  }

  float invl[4];
  #pragma unroll
  for (int ns = 0; ns < 4; ++ns) {
    float v = lpart[ns];
    v += __shfl_xor(v, 16);
    v += __shfl_xor(v, 32);
    invl[ns] = 1.0f / v;
  }

  // ---- epilogue: sigmoid gate from gacc (cold), write O fp16 (i,h,s,d) ----
  #pragma unroll
  for (int ns = 0; ns < 4; ++ns) {
    const int s = s_base + ns * 16 + lr;
    #pragma unroll
    for (int md = 0; md < 2; ++md) {
      const int d0 = md * 16 + quad * 4;
      float4 bgv = *(const float4*)(bg + h * 32 + d0);
      float g0 = 1.0f / (1.0f + __expf(-(gacc[md][ns][0] + bgv.x)));
      float g1 = 1.0f / (1.0f + __expf(-(gacc[md][ns][1] + bgv.y)));
      float g2 = 1.0f / (1.0f + __expf(-(gacc[md][ns][2] + bgv.z)));
      float g3 = 1.0f / (1.0f + __expf(-(gacc[md][ns][3] + bgv.w)));
      ushort4 ov;
      ov.x = f2h(g0 * oacc[md][ns][0] * invl[ns]);
      ov.y = f2h(g1 * oacc[md][ns][1] * invl[ns]);
      ov.z = f2h(g2 * oacc[md][ns][2] * invl[ns]);
      ov.w = f2h(g3 * oacc[md][ns][3] * invl[ns]);
      *(ushort4*)(Oh + hbase + (size_t)s * HEAD_DIM + d0) = ov;
    }
  }
}

// ---------------------------------------------------------------------------
// out: fp16 GEMM, NOW SOFTWARE-PIPELINED (T3/T4 recipe).
// A = O fp16 (i,h,s,d); B = Wo^T fp16 [n][k].
// BK=32 (one head per iter, 8 iters), 2-stage LDS double buffer (32 KB
// total, same as before). Next stage's 4 global_load_lds are issued BEFORE
// computing the current stage; wait = counted vmcnt(4) + RAW s_barrier.
// __syncthreads() is never used in the loop (it drains vmcnt to 0 -> the
// old fully-serial behavior: sync -> load -> drain -> compute).
// ---------------------------------------------------------------------------
__global__ __launch_bounds__(256) void out_kernel(
    const ushort* __restrict__ Oh, const ushort* __restrict__ Woh,
    const float* __restrict__ bo, float* __restrict__ out) {
  __shared__ __align__(16) ushort As[2][128 * 32];   // 2 x 8 KB
  __shared__ __align__(16) ushort Bs[2][128 * 32];   // 2 x 8 KB

  const int bid = blockIdx.x;                    // 0..1023
  const int xcd = bid & 7;
  const int j   = bid >> 3;                      // 0..127
  const int ntile = j & 1;
  const int rg    = (xcd << 6) + (j >> 1);       // 0..511
  const int n0 = ntile * 128;
  const int s  = rg >> 1;
  const int i0 = (rg & 1) * 128;
  const int tid = threadIdx.x;
  const int wave = tid >> 6, lane = tid & 63;
  const int wm = wave >> 1, wn = wave & 1;
  const int lr = lane & 15, quad = lane >> 4;
  const int fsw = (quad ^ ((lr >> 1) & 3)) * 8;

  const int slot = wave * 64 + lane;
  const int row0 = slot >> 2;                    // 0..63
  const int kc   = ((slot & 3) ^ ((row0 >> 1) & 3)) * 8;

  // per-iter: A advances one head (8192 ushorts), B one 32-k chunk.
  const ushort* pA = Oh + (size_t)(i0 + row0) * 65536 + (size_t)s * 32 + kc;
  const ushort* pB = Woh + (size_t)(n0 + row0) * 256 + kc;
  const int ld0 = wave * 512;                    // rows 0..63
  const int ld1 = 2048 + wave * 512;             // rows 64..127

  f32x4 acc[4][4] = {};

  // stage kk into buf: 4 gl16 per wave (A rows 0-63, 64-127; B same)
  #define STAGE(buf, kk)                                                     \
    do {                                                                     \
      const ushort* a_ = pA + (size_t)(kk) * 8192;                           \
      const ushort* b_ = pB + (kk) * 32;                                     \
      gl16(a_,                      As[buf] + ld0);                          \
      gl16(a_ + (size_t)64 * 65536, As[buf] + ld1);                          \
      gl16(b_,                      Bs[buf] + ld0);                          \
      gl16(b_ + 64 * 256,           Bs[buf] + ld1);                          \
    } while (0)

  STAGE(0, 0);
  int cur = 0;
  #pragma unroll 1
  for (int kk = 0; kk < 8; ++kk) {
    if (kk < 7) {
      STAGE(cur ^ 1, kk + 1);                       // next tile in flight
      asm volatile("s_waitcnt vmcnt(4)" ::: "memory");  // current tile landed
    } else {
      asm volatile("s_waitcnt vmcnt(0)" ::: "memory");
    }
    __builtin_amdgcn_s_barrier();                   // all waves' tile visible

    f16x8 a0[4], b0[4];
    #pragma unroll
    for (int mt = 0; mt < 4; ++mt)
      a0[mt] = *(const f16x8*)&As[cur][(wm * 64 + mt * 16 + lr) * 32 + fsw];
    #pragma unroll
    for (int nt = 0; nt < 4; ++nt)
      b0[nt] = *(const f16x8*)&Bs[cur][(wn * 64 + nt * 16 + lr) * 32 + fsw];
    #pragma unroll
    for (int mt = 0; mt < 4; ++mt)
      #pragma unroll
      for (int nt = 0; nt < 4; ++nt)
        acc[mt][nt] = __builtin_amdgcn_mfma_f32_16x16x32_f16(a0[mt], b0[nt], acc[mt][nt], 0, 0, 0);

    __builtin_amdgcn_s_barrier();                   // buf[cur] free to refill
    cur ^= 1;
  }
  #undef STAGE

  #pragma unroll
  for (int nt = 0; nt < 4; ++nt) {
    const int col = n0 + wn * 64 + nt * 16 + lr;
    const float b = bo[col];
    #pragma unroll
    for (int mt = 0; mt < 4; ++mt)
      #pragma unroll
      for (int reg = 0; reg < 4; ++reg) {
        const int mloc = wm * 64 + mt * 16 + quad * 4 + reg;
        out[((size_t)s * 256 + i0 + mloc) * C_S + col] = acc[mt][nt][reg] + b;
      }
  }
}

// ---------------------------------------------------------------------------
extern "C" void kernel_launch(void* const* d_in, const int* in_sizes, int n_in,
                              void* d_out, int out_size, void* d_ws, size_t ws_size,
                              hipStream_t stream) {
  const float* msa   = (const float*)d_in[0];
  const float* gamma = (const float*)d_in[1];
  const float* beta  = (const float*)d_in[2];
  const float* Wq    = (const float*)d_in[3];
  const float* Wk    = (const float*)d_in[4];
  const float* Wv    = (const float*)d_in[5];
  const float* Wg    = (const float*)d_in[6];
  const float* bg    = (const float*)d_in[7];
  const float* Wo    = (const float*)d_in[8];
  const float* bo    = (const float*)d_in[9];
  float* out = (float*)d_out;

  const size_t PLANE = (size_t)NROWS * TOTAL;    // 16.78M elements
  // ws: O fp16 (33.5 MB) + W fp16 (0.66 MB)
  ushort* Oh  = (ushort*)d_ws;                   // (i,h,s,d)
  ushort* Wch = Oh + PLANE;                      // [1024][256]
  ushort* Woh = Wch + 1024 * 256;                // [256][256]
  // X fp16 lives in d_out (33.5 MB of 67 MB, dead before out_kernel writes)
  ushort* Xh = (ushort*)d_out;

  prep_w_kernel<<<1280, 256, 0, stream>>>(Wq, Wk, Wv, Wg, Wo, Wch, Woh);
  prep_x_kernel<<<NROWS / 4, 256, 0, stream>>>(msa, gamma, beta, Xh);
  fused_attn_kernel<<<I_DIM * NUM_HEADS, 256, 0, stream>>>(Xh, Wch, bg, Oh);
  out_kernel<<<1024, 256, 0, stream>>>(Oh, Woh, bo, out);
}

// Round 9
// 273.186 us; speedup vs baseline: 1.2941x; 1.0314x over previous
//
#include <hip/hip_runtime.h>
#include <hip/hip_fp16.h>
#include <math.h>

#define C_S 256
#define NUM_HEADS 8
#define HEAD_DIM 32
#define TOTAL 256
#define S_DIM 256
#define I_DIM 256
#define NROWS (S_DIM * I_DIM)   // 65536
#define LN_EPS 1e-5f
#define QSCALE 0.25503534f      // log2(e)/sqrt(32)

typedef _Float16 f16x8 __attribute__((ext_vector_type(8)));   // 8 fp16 = 4 VGPR
typedef __attribute__((ext_vector_type(4))) float f32x4;

__device__ __forceinline__ ushort f2h(float x) {
  return __half_as_ushort(__float2half(x));      // RNE
}
__device__ __forceinline__ float h2f(ushort u) {
  return __half2float(__ushort_as_half(u));
}
// pack two f32 -> two fp16 (RTZ) in one VALU op; returns the 32-bit word.
// RTZ is used ONLY for P (validated); K/V/Q/G/O stay RNE — absmax margin
// is tight (1.953e-3) and must not grow.
__device__ __forceinline__ uint pkrtz(float a, float b) {
  return __builtin_bit_cast(uint, __builtin_amdgcn_cvt_pkrtz(a, b));
}
// async global->LDS, 16B per lane; lds base must be wave-uniform.
__device__ __forceinline__ void gl16(const void* g, void* l) {
  __builtin_amdgcn_global_load_lds(
      (const __attribute__((address_space(1))) unsigned*)g,
      (__attribute__((address_space(3))) unsigned*)l, 16, 0, 0);
}
// quad all-to-all within same lr: inputs (x0 = block0 dword, x1 = block1 dword)
// outputs: o0 = dword for src-quads {2(q&1)}, o1 = for {2(q&1)+1}, block q>>1.
__device__ __forceinline__ void quadx(uint x0, uint x1, uint& o0, uint& o1) {
  auto a = __builtin_amdgcn_permlane32_swap(x0, x1, false, false);
  auto b = __builtin_amdgcn_permlane16_swap(a[0], a[1], false, false);
  o0 = b[0]; o1 = b[1];
}

// ---------------------------------------------------------------------------
// prep: ONE launch doing both weight prep and X prep (fewer dispatches).
//  blocks [0, 16384): LN + fp16 X, written I-MAJOR: Xh row = i*256 + s.
//    -> one fused block's X (fixed i, all s) is a contiguous 128 KB extent,
//       shared L2-locally by the 8 head-blocks of that i.
//  blocks [16384, 17664): weight transpose + fp16.
// ---------------------------------------------------------------------------
__global__ __launch_bounds__(256) void prep_kernel(
    const float* __restrict__ msa, const float* __restrict__ gamma,
    const float* __restrict__ beta,
    const float* __restrict__ Wq, const float* __restrict__ Wk,
    const float* __restrict__ Wv, const float* __restrict__ Wg,
    const float* __restrict__ Wo,
    ushort* __restrict__ Xh, ushort* __restrict__ Wch,
    ushort* __restrict__ Woh) {
  const int bid = blockIdx.x;
  if (bid < 16384) {
    const int row  = bid * 4 + (threadIdx.x >> 6);   // msa row = s*256 + i
    const int lane = threadIdx.x & 63;
    float4 v = ((const float4*)(msa + (size_t)row * C_S))[lane];
    float sum = v.x + v.y + v.z + v.w;
    float sq  = v.x*v.x + v.y*v.y + v.z*v.z + v.w*v.w;
    #pragma unroll
    for (int off = 1; off < 64; off <<= 1) {
      sum += __shfl_xor(sum, off);
      sq  += __shfl_xor(sq, off);
    }
    float mu = sum * (1.0f / 256.0f);
    float rs = rsqrtf(sq * (1.0f / 256.0f) - mu * mu + LN_EPS);
    float4 gv = ((const float4*)gamma)[lane];
    float4 bv = ((const float4*)beta)[lane];
    ushort4 hh;
    hh.x = f2h((v.x - mu) * rs * gv.x + bv.x);
    hh.y = f2h((v.y - mu) * rs * gv.y + bv.y);
    hh.z = f2h((v.z - mu) * rs * gv.z + bv.z);
    hh.w = f2h((v.w - mu) * rs * gv.w + bv.w);
    // i-major: dst row = i*256 + s  (msa row r: s = r>>8, i = r&255)
    const int drow = ((row & 255) << 8) + (row >> 8);
    *(ushort4*)(Xh + (size_t)drow * 256 + lane * 4) = hh;
  } else {
    const int b = bid - 16384;           // 0..1279
    const int mat = b >> 8, n = b & 255;
    const int k = threadIdx.x;
    const float* W = (mat == 0) ? Wq : (mat == 1) ? Wk
                    : (mat == 2) ? Wv : (mat == 3) ? Wg : Wo;
    ushort h = f2h(W[(size_t)k * 256 + n]);
    if (mat < 4) Wch[((size_t)(mat * 256 + n)) * 256 + k] = h;
    else         Woh[(size_t)n * 256 + k] = h;
  }
}

// ---------------------------------------------------------------------------
// fused_attn: R5/R8 champion structure; ONLY change = i-major X addressing.
// one block per (i,h); 256 threads / 4 waves; wave owns 64 rows.
//  LDS 36.5 KB: Kls[256][40] K[t][d] + Vth[32][264] V^T[d][t].
//  P never touches LDS (permlane quad-exchange); gacc rides AGPRs to the
//  epilogue. (256,3): 170-reg unified budget >= ~130 live set -> no spill.
//  CLOSED: (256,4) tried 3x (R4/R6/R7) -> allocator splits 64/64 and
//  spills ~0.1-0.5 GB scratch every time. Do not retry.
// ---------------------------------------------------------------------------
__global__ __launch_bounds__(256, 3) void fused_attn_kernel(
    const ushort* __restrict__ Xh,    // [65536][256], row = i*256+s (I-MAJOR)
    const ushort* __restrict__ Wch,   // [1024][256], row = mat*256+n
    const float* __restrict__ bg,
    ushort* __restrict__ Oh) {        // (i,h,s,d) fp16
  __shared__ __align__(16) ushort Kls[256][40];   // 20.0 KB  K[t][d]
  __shared__ __align__(16) ushort Vth[32][264];   // 16.5 KB  V^T[d][t]

  const int bid = blockIdx.x;
  const int xcd = bid & 7, j = bid >> 3;
  const int h = j & 7;
  const int i = (xcd << 5) + (j >> 3);            // 32 consecutive i per XCD
  const int ih = i * NUM_HEADS + h;
  const int tid = threadIdx.x;
  const int wave = tid >> 6, lane = tid & 63;
  const int lr = lane & 15, quad = lane >> 4;
  const int s_base = wave * 64;
  const size_t hbase = (size_t)ih * (S_DIM * HEAD_DIM);

  // X B-frag base (i-major): row = i*256 + (s_base+lr); rows 512 B apart,
  // whole block's X = one contiguous 128 KB extent (L2-local across heads).
  const ushort* xr0 = Xh + ((size_t)i * 256 + (s_base + lr)) * 256 + quad * 8;
  // W^T A-frag base: row = mat*256 + h*32 + (mt*16+lr)
  const ushort* wr0 = Wch + ((size_t)(h * 32 + lr)) * 256 + quad * 8;

  // ---- Phase A: K^T (mat 1), V^T (mat 2, swapped operands) ----
  f32x4 kacc[2][4] = {}, vacc[2][4] = {};
  #pragma unroll
  for (int kb = 0; kb < 8; ++kb) {
    f16x8 xb[4];
    #pragma unroll
    for (int nt = 0; nt < 4; ++nt)
      xb[nt] = *(const f16x8*)(xr0 + (size_t)nt * 16 * 256 + kb * 32);
    f16x8 wk[2], wv[2];
    #pragma unroll
    for (int mt = 0; mt < 2; ++mt) {
      wk[mt] = *(const f16x8*)(wr0 + (size_t)1 * 65536 + mt * 4096 + kb * 32);
      wv[mt] = *(const f16x8*)(wr0 + (size_t)2 * 65536 + mt * 4096 + kb * 32);
    }
    #pragma unroll
    for (int mt = 0; mt < 2; ++mt)
      #pragma unroll
      for (int nt = 0; nt < 4; ++nt) {
        kacc[mt][nt] = __builtin_amdgcn_mfma_f32_16x16x32_f16(wk[mt], xb[nt], kacc[mt][nt], 0, 0, 0);
        // swapped: D col = d (lr), row = t (quad*4+reg) -> packed V^T store
        vacc[mt][nt] = __builtin_amdgcn_mfma_f32_16x16x32_f16(xb[nt], wv[mt], vacc[mt][nt], 0, 0, 0);
      }
  }
  #pragma unroll
  for (int mt = 0; mt < 2; ++mt)
    #pragma unroll
    for (int nt = 0; nt < 4; ++nt) {
      // K: D col = t (nt*16+lr), row = d (mt*16+quad*4+reg)
      const int t = s_base + nt * 16 + lr;
      ushort4 kp;
      kp.x = f2h(kacc[mt][nt][0]); kp.y = f2h(kacc[mt][nt][1]);
      kp.z = f2h(kacc[mt][nt][2]); kp.w = f2h(kacc[mt][nt][3]);
      *(ushort4*)&Kls[t][mt * 16 + quad * 4] = kp;
      // V (swapped): lane holds V^T[d = mt*16+lr][t = s_base+nt*16+quad*4+reg]
      ushort4 vp;
      vp.x = f2h(vacc[mt][nt][0]); vp.y = f2h(vacc[mt][nt][1]);
      vp.z = f2h(vacc[mt][nt][2]); vp.w = f2h(vacc[mt][nt][3]);
      *(ushort4*)&Vth[mt * 16 + lr][s_base + nt * 16 + quad * 4] = vp;
    }

  // ---- Phase B: Q^T (mat 0), G^T (mat 3) ----
  f32x4 qacc[2][4] = {}, gacc[2][4] = {};
  #pragma unroll
  for (int kb = 0; kb < 8; ++kb) {
    f16x8 xb[4];
    #pragma unroll
    for (int nt = 0; nt < 4; ++nt)
      xb[nt] = *(const f16x8*)(xr0 + (size_t)nt * 16 * 256 + kb * 32);
    f16x8 wq[2], wg[2];
    #pragma unroll
    for (int mt = 0; mt < 2; ++mt) {
      wq[mt] = *(const f16x8*)(wr0 + (size_t)0 * 65536 + mt * 4096 + kb * 32);
      wg[mt] = *(const f16x8*)(wr0 + (size_t)3 * 65536 + mt * 4096 + kb * 32);
    }
    #pragma unroll
    for (int mt = 0; mt < 2; ++mt)
      #pragma unroll
      for (int nt = 0; nt < 4; ++nt) {
        qacc[mt][nt] = __builtin_amdgcn_mfma_f32_16x16x32_f16(wq[mt], xb[nt], qacc[mt][nt], 0, 0, 0);
        gacc[mt][nt] = __builtin_amdgcn_mfma_f32_16x16x32_f16(wg[mt], xb[nt], gacc[mt][nt], 0, 0, 0);
      }
  }
  // Q -> B-operand frags purely in registers via quad exchange (RNE pack).
  f16x8 qf[4];
  #pragma unroll
  for (int ns = 0; ns < 4; ++ns) {
    uint x0 = (uint)f2h(qacc[0][ns][0] * QSCALE) | ((uint)f2h(qacc[0][ns][1] * QSCALE) << 16);
    uint y0 = (uint)f2h(qacc[0][ns][2] * QSCALE) | ((uint)f2h(qacc[0][ns][3] * QSCALE) << 16);
    uint x1 = (uint)f2h(qacc[1][ns][0] * QSCALE) | ((uint)f2h(qacc[1][ns][1] * QSCALE) << 16);
    uint y1 = (uint)f2h(qacc[1][ns][2] * QSCALE) | ((uint)f2h(qacc[1][ns][3] * QSCALE) << 16);
    uint qa, qb, qc, qd2;
    quadx(x0, x1, qa, qb);
    quadx(y0, y1, qc, qd2);
    uint4 qw4 = make_uint4(qa, qc, qb, qd2);
    qf[ns] = __builtin_bit_cast(f16x8, qw4);
  }

  __syncthreads();   // K/V visible (only cross-wave data)

  // ---- attention chunk loop; P stays in registers (permlane shuffle) ----
  f32x4 oacc[2][4] = {};
  float lpart[4] = {};
  #pragma unroll 1
  for (int c = 0; c < 4; ++c) {
    const int t0 = c * 64;
    #pragma unroll
    for (int half = 0; half < 2; ++half) {
      f16x8 kf0 = *(const f16x8*)&Kls[t0 + (half * 2 + 0) * 16 + lr][quad * 8];
      f16x8 kf1 = *(const f16x8*)&Kls[t0 + (half * 2 + 1) * 16 + lr][quad * 8];
      const int tq = t0 + half * 32 + quad * 8;
      f16x8 v0 = *(const f16x8*)&Vth[lr][tq];
      f16x8 v1 = *(const f16x8*)&Vth[16 + lr][tq];
      #pragma unroll
      for (int ns = 0; ns < 4; ++ns) {
        f32x4 s0 = {}, s1 = {};
        s0 = __builtin_amdgcn_mfma_f32_16x16x32_f16(kf0, qf[ns], s0, 0, 0, 0);
        s1 = __builtin_amdgcn_mfma_f32_16x16x32_f16(kf1, qf[ns], s1, 0, 0, 0);
        float e00 = exp2f(s0[0]), e01 = exp2f(s0[1]);
        float e02 = exp2f(s0[2]), e03 = exp2f(s0[3]);
        float e10 = exp2f(s1[0]), e11 = exp2f(s1[1]);
        float e12 = exp2f(s1[2]), e13 = exp2f(s1[3]);
        lpart[ns] += ((e00 + e01) + (e02 + e03)) + ((e10 + e11) + (e12 + e13));
        uint x0 = pkrtz(e00, e01), y0 = pkrtz(e02, e03);
        uint x1 = pkrtz(e10, e11), y1 = pkrtz(e12, e13);
        uint pa, pb, pc, pd;
        quadx(x0, x1, pa, pb);
        quadx(y0, y1, pc, pd);
        uint4 pw4 = make_uint4(pa, pc, pb, pd);
        f16x8 pf = __builtin_bit_cast(f16x8, pw4);
        __builtin_amdgcn_s_setprio(1);
        oacc[0][ns] = __builtin_amdgcn_mfma_f32_16x16x32_f16(v0, pf, oacc[0][ns], 0, 0, 0);
        oacc[1][ns] = __builtin_amdgcn_mfma_f32_16x16x32_f16(v1, pf, oacc[1][ns], 0, 0, 0);
        __builtin_amdgcn_s_setprio(0);
      }
    }
  }

  float invl[4];
  #pragma unroll
  for (int ns = 0; ns < 4; ++ns) {
    float v = lpart[ns];
    v += __shfl_xor(v, 16);
    v += __shfl_xor(v, 32);
    invl[ns] = 1.0f / v;
  }

  // ---- epilogue: sigmoid gate from gacc (cold), write O fp16 (i,h,s,d) ----
  #pragma unroll
  for (int ns = 0; ns < 4; ++ns) {
    const int s = s_base + ns * 16 + lr;
    #pragma unroll
    for (int md = 0; md < 2; ++md) {
      const int d0 = md * 16 + quad * 4;
      float4 bgv = *(const float4*)(bg + h * 32 + d0);
      float g0 = 1.0f / (1.0f + __expf(-(gacc[md][ns][0] + bgv.x)));
      float g1 = 1.0f / (1.0f + __expf(-(gacc[md][ns][1] + bgv.y)));
      float g2 = 1.0f / (1.0f + __expf(-(gacc[md][ns][2] + bgv.z)));
      float g3 = 1.0f / (1.0f + __expf(-(gacc[md][ns][3] + bgv.w)));
      ushort4 ov;
      ov.x = f2h(g0 * oacc[md][ns][0] * invl[ns]);
      ov.y = f2h(g1 * oacc[md][ns][1] * invl[ns]);
      ov.z = f2h(g2 * oacc[md][ns][2] * invl[ns]);
      ov.w = f2h(g3 * oacc[md][ns][3] * invl[ns]);
      *(ushort4*)(Oh + hbase + (size_t)s * HEAD_DIM + d0) = ov;
    }
  }
}

// ---------------------------------------------------------------------------
// out: fp16 GEMM, software-pipelined (R8: counted vmcnt + raw barriers).
// A = O fp16 (i,h,s,d); B = Wo^T fp16 [n][k]. BK=32, 2-stage LDS dbuf.
// ---------------------------------------------------------------------------
__global__ __launch_bounds__(256) void out_kernel(
    const ushort* __restrict__ Oh, const ushort* __restrict__ Woh,
    const float* __restrict__ bo, float* __restrict__ out) {
  __shared__ __align__(16) ushort As[2][128 * 32];   // 2 x 8 KB
  __shared__ __align__(16) ushort Bs[2][128 * 32];   // 2 x 8 KB

  const int bid = blockIdx.x;                    // 0..1023
  const int xcd = bid & 7;
  const int j   = bid >> 3;                      // 0..127
  const int ntile = j & 1;
  const int rg    = (xcd << 6) + (j >> 1);       // 0..511
  const int n0 = ntile * 128;
  const int s  = rg >> 1;
  const int i0 = (rg & 1) * 128;
  const int tid = threadIdx.x;
  const int wave = tid >> 6, lane = tid & 63;
  const int wm = wave >> 1, wn = wave & 1;
  const int lr = lane & 15, quad = lane >> 4;
  const int fsw = (quad ^ ((lr >> 1) & 3)) * 8;

  const int slot = wave * 64 + lane;
  const int row0 = slot >> 2;                    // 0..63
  const int kc   = ((slot & 3) ^ ((row0 >> 1) & 3)) * 8;

  const ushort* pA = Oh + (size_t)(i0 + row0) * 65536 + (size_t)s * 32 + kc;
  const ushort* pB = Woh + (size_t)(n0 + row0) * 256 + kc;
  const int ld0 = wave * 512;
  const int ld1 = 2048 + wave * 512;

  f32x4 acc[4][4] = {};

  #define STAGE(buf, kk)                                                     \
    do {                                                                     \
      const ushort* a_ = pA + (size_t)(kk) * 8192;                           \
      const ushort* b_ = pB + (kk) * 32;                                     \
      gl16(a_,                      As[buf] + ld0);                          \
      gl16(a_ + (size_t)64 * 65536, As[buf] + ld1);                          \
      gl16(b_,                      Bs[buf] + ld0);                          \
      gl16(b_ + 64 * 256,           Bs[buf] + ld1);                          \
    } while (0)

  STAGE(0, 0);
  int cur = 0;
  #pragma unroll 1
  for (int kk = 0; kk < 8; ++kk) {
    if (kk < 7) {
      STAGE(cur ^ 1, kk + 1);                       // next tile in flight
      asm volatile("s_waitcnt vmcnt(4)" ::: "memory");  // current tile landed
    } else {
      asm volatile("s_waitcnt vmcnt(0)" ::: "memory");
    }
    __builtin_amdgcn_s_barrier();                   // all waves' tile visible

    f16x8 a0[4], b0[4];
    #pragma unroll
    for (int mt = 0; mt < 4; ++mt)
      a0[mt] = *(const f16x8*)&As[cur][(wm * 64 + mt * 16 + lr) * 32 + fsw];
    #pragma unroll
    for (int nt = 0; nt < 4; ++nt)
      b0[nt] = *(const f16x8*)&Bs[cur][(wn * 64 + nt * 16 + lr) * 32 + fsw];
    #pragma unroll
    for (int mt = 0; mt < 4; ++mt)
      #pragma unroll
      for (int nt = 0; nt < 4; ++nt)
        acc[mt][nt] = __builtin_amdgcn_mfma_f32_16x16x32_f16(a0[mt], b0[nt], acc[mt][nt], 0, 0, 0);

    __builtin_amdgcn_s_barrier();                   // buf[cur] free to refill
    cur ^= 1;
  }
  #undef STAGE

  #pragma unroll
  for (int nt = 0; nt < 4; ++nt) {
    const int col = n0 + wn * 64 + nt * 16 + lr;
    const float b = bo[col];
    #pragma unroll
    for (int mt = 0; mt < 4; ++mt)
      #pragma unroll
      for (int reg = 0; reg < 4; ++reg) {
        const int mloc = wm * 64 + mt * 16 + quad * 4 + reg;
        out[((size_t)s * 256 + i0 + mloc) * C_S + col] = acc[mt][nt][reg] + b;
      }
  }
}

// ---------------------------------------------------------------------------
extern "C" void kernel_launch(void* const* d_in, const int* in_sizes, int n_in,
                              void* d_out, int out_size, void* d_ws, size_t ws_size,
                              hipStream_t stream) {
  const float* msa   = (const float*)d_in[0];
  const float* gamma = (const float*)d_in[1];
  const float* beta  = (const float*)d_in[2];
  const float* Wq    = (const float*)d_in[3];
  const float* Wk    = (const float*)d_in[4];
  const float* Wv    = (const float*)d_in[5];
  const float* Wg    = (const float*)d_in[6];
  const float* bg    = (const float*)d_in[7];
  const float* Wo    = (const float*)d_in[8];
  const float* bo    = (const float*)d_in[9];
  float* out = (float*)d_out;

  const size_t PLANE = (size_t)NROWS * TOTAL;    // 16.78M elements
  // ws: O fp16 (33.5 MB) + W fp16 (0.66 MB)
  ushort* Oh  = (ushort*)d_ws;                   // (i,h,s,d)
  ushort* Wch = Oh + PLANE;                      // [1024][256]
  ushort* Woh = Wch + 1024 * 256;                // [256][256]
  // X fp16 lives in d_out (33.5 MB of 67 MB, dead before out_kernel writes)
  ushort* Xh = (ushort*)d_out;                   // i-major: row = i*256+s

  prep_kernel<<<16384 + 1280, 256, 0, stream>>>(msa, gamma, beta,
                                                Wq, Wk, Wv, Wg, Wo,
                                                Xh, Wch, Woh);
  fused_attn_kernel<<<I_DIM * NUM_HEADS, 256, 0, stream>>>(Xh, Wch, bg, Oh);
  out_kernel<<<1024, 256, 0, stream>>>(Oh, Woh, bo, out);
}